// Round 3
// baseline (663.427 us; speedup 1.0000x reference)
//
#include <hip/hip_runtime.h>

#define B_ 8
#define C_ 64
#define T_ 256
#define F_ 256
#define H_ 128
#define TF_ (T_*F_)

typedef _Float16 half_t;
typedef _Float16 half8 __attribute__((ext_vector_type(8)));
typedef float float4v __attribute__((ext_vector_type(4)));

#if __has_builtin(__builtin_amdgcn_exp2f)
#define EXP2F(x) __builtin_amdgcn_exp2f(x)
#else
static __device__ inline float EXP2F(float x) { float r; asm("v_exp_f32 %0, %1" : "=v"(r) : "v"(x)); return r; }
#endif
#if __has_builtin(__builtin_amdgcn_rcpf)
#define RCPF(x) __builtin_amdgcn_rcpf(x)
#else
static __device__ inline float RCPF(float x) { float r; asm("v_rcp_f32 %0, %1" : "=v"(r) : "v"(x)); return r; }
#endif

#define NEG_L2E  (-1.4426950408889634f)
#define NEG_2L2E (-2.8853900817779268f)

// ---------------- Kernel 1: x [B,C,T,F] fp32 -> xt [B, T*F, C] fp16 ----------------
__global__ __launch_bounds__(256) void k_transpose(const float* __restrict__ x,
                                                   half_t* __restrict__ xt) {
    __shared__ float lds[64 * 65];
    int blk = blockIdx.x;
    int b   = blk >> 10;            // /1024
    int tf0 = (blk & 1023) << 6;    // *64
    int tid = threadIdx.x;
    int s = tid & 15;               // tf sub-tile (x4)
    int q = tid >> 4;               // 0..15 c base
    const float* xp = x + (size_t)(b * C_) * TF_ + tf0 + s * 4;
#pragma unroll
    for (int i = 0; i < 4; ++i) {
        int c = q + i * 16;
        float4v v = *(const float4v*)(xp + (size_t)c * TF_);
#pragma unroll
        for (int j = 0; j < 4; ++j) lds[(s * 4 + j) * 65 + c] = v[j];
    }
    __syncthreads();
    int row = tid >> 2;             // 0..63 (tf local)
    int c0  = (tid & 3) << 4;       // 0,16,32,48
    float v[16];
#pragma unroll
    for (int k = 0; k < 16; ++k) v[k] = lds[row * 65 + c0 + k];
    half8 o0, o1;
#pragma unroll
    for (int k = 0; k < 8; ++k) { o0[k] = (half_t)v[k]; o1[k] = (half_t)v[8 + k]; }
    half_t* op = xt + ((size_t)b * TF_ + tf0 + row) * C_ + c0;
    *(half8*)op       = o0;
    *(half8*)(op + 8) = o1;
}

// ---------------- Kernel 2: fused dual GRU, MFMA 16x16x32 f16, M=8/block ----------------
__device__ inline half8 load_w8s(const float* __restrict__ p, float s) {
    half8 r;
#pragma unroll
    for (int k = 0; k < 8; ++k) r[k] = (half_t)(p[k] * s);
    return r;
}

#define MFMA(a, b, c) __builtin_amdgcn_mfma_f32_16x16x32_f16((a), (b), (c), 0, 0, 0)

// 512 blocks (256 time + 256 freq), 512 thr = 8 waves; block owns M=8 sequences
// (MFMA rows m and m+8 duplicate the same sequence; quads 2,3 compute dups and
// don't store). 2 blocks/CU -> 4 waves/SIMD for latency hiding.
// A-frag: lane holds A[m=lane&15][k=quad*8+j]; B-frag: B[k=quad*8+j][n=lane&15];
// C/D: lane holds D[m=quad*4+reg][n=lane&15].
__global__ __launch_bounds__(512, 4) void k_gru(
    const half_t* __restrict__ xt,
    const float* __restrict__ Wih_t, const float* __restrict__ Whh_t,
    const float* __restrict__ bih_t, const float* __restrict__ bhh_t,
    const float* __restrict__ Wih_f, const float* __restrict__ Whh_f,
    const float* __restrict__ bih_f, const float* __restrict__ bhh_f,
    float* __restrict__ h_t_out, float* __restrict__ h_f_out) {
    __shared__ half_t hbuf0[8 * 136];
    __shared__ half_t hbuf1[8 * 136];

    int tid  = threadIdx.x;
    int w    = tid >> 6;
    int lane = tid & 63;
    int nidx = lane & 15;
    int quad = lane >> 4;
    int arow = nidx & 7;          // A-operand sequence row (dup for nidx>=8)

    int bi  = blockIdx.x;
    bool isf = bi >= 256;
    int lbi = bi & 255;
    int b   = lbi >> 5;
    int g8  = (lbi & 31) << 3;    // f0 (time) or t0 (freq)

    const float* Wih = isf ? Wih_f : Wih_t;
    const float* Whh = isf ? Whh_f : Whh_t;
    const float* bih = isf ? bih_f : bih_t;
    const float* bhh = isf ? bhh_f : bhh_t;
    float* hout      = isf ? h_f_out : h_t_out;

    size_t Sm = isf ? (size_t)(F_ * C_) : (size_t)C_;   // stride between sequences
    size_t Ss = isf ? (size_t)C_ : (size_t)(F_ * C_);   // stride per recurrence step
    size_t abase = (size_t)b * TF_ * C_ + (size_t)g8 * Sm;

    // ---- weight B-fragments in registers (loaded once, pre-scaled) ----
    int gr = w * 16 + nidx;     // r gate row  [0,128)
    int gz = gr + 128;          // z gate row
    int gn = gr + 256;          // n gate row
    int ko = quad * 8;

    half8 wir0 = load_w8s(Wih + gr * 64 + ko,      NEG_L2E);
    half8 wir1 = load_w8s(Wih + gr * 64 + 32 + ko, NEG_L2E);
    half8 wiz0 = load_w8s(Wih + gz * 64 + ko,      NEG_L2E);
    half8 wiz1 = load_w8s(Wih + gz * 64 + 32 + ko, NEG_L2E);
    half8 win0 = load_w8s(Wih + gn * 64 + ko,      NEG_2L2E);
    half8 win1 = load_w8s(Wih + gn * 64 + 32 + ko, NEG_2L2E);
    half8 whr[4], whz[4], whn[4];
#pragma unroll
    for (int kt = 0; kt < 4; ++kt) {
        whr[kt] = load_w8s(Whh + gr * 128 + kt * 32 + ko, NEG_L2E);
        whz[kt] = load_w8s(Whh + gz * 128 + kt * 32 + ko, NEG_L2E);
        whn[kt] = load_w8s(Whh + gn * 128 + kt * 32 + ko, NEG_2L2E);
    }
    float br  = NEG_L2E  * (bih[gr] + bhh[gr]);
    float bz  = NEG_L2E  * (bih[gz] + bhh[gz]);
    float bin = NEG_2L2E * bih[gn];
    float bhn = NEG_2L2E * bhh[gn];

    for (int idx = tid; idx < 8 * 136; idx += 512) hbuf0[idx] = (half_t)0.f;
    float h_old[4] = {0.f, 0.f, 0.f, 0.f};
    __syncthreads();

    const half_t* ap = xt + abase + (size_t)arow * Sm + ko;
    half8 xaA0 = *(const half8*)ap;
    half8 xaA1 = *(const half8*)(ap + 32);
    ap += Ss;
    half8 xaB0, xaB1;

#define GRU_STEP(XA0, XA1, RBUF, WBUF)                                          \
    {                                                                           \
        const half_t* hrow = (RBUF) + arow * 136 + ko;                          \
        half8 ha0 = *(const half8*)(hrow);                                      \
        half8 ha1 = *(const half8*)(hrow + 32);                                 \
        half8 ha2 = *(const half8*)(hrow + 64);                                 \
        half8 ha3 = *(const half8*)(hrow + 96);                                 \
        float4v ar  = {br, br, br, br};                                         \
        float4v az  = {bz, bz, bz, bz};                                         \
        float4v ain = {bin, bin, bin, bin};                                     \
        float4v ahn = {bhn, bhn, bhn, bhn};                                     \
        ar  = MFMA(XA0, wir0, ar);  ar  = MFMA(XA1, wir1, ar);                  \
        az  = MFMA(XA0, wiz0, az);  az  = MFMA(XA1, wiz1, az);                  \
        ain = MFMA(XA0, win0, ain); ain = MFMA(XA1, win1, ain);                 \
        ar  = MFMA(ha0, whr[0], ar);  ar  = MFMA(ha1, whr[1], ar);              \
        ar  = MFMA(ha2, whr[2], ar);  ar  = MFMA(ha3, whr[3], ar);              \
        az  = MFMA(ha0, whz[0], az);  az  = MFMA(ha1, whz[1], az);              \
        az  = MFMA(ha2, whz[2], az);  az  = MFMA(ha3, whz[3], az);              \
        ahn = MFMA(ha0, whn[0], ahn); ahn = MFMA(ha1, whn[1], ahn);             \
        ahn = MFMA(ha2, whn[2], ahn); ahn = MFMA(ha3, whn[3], ahn);             \
        _Pragma("unroll")                                                       \
        for (int rg = 0; rg < 4; ++rg) {                                        \
            float r  = RCPF(1.f + EXP2F(ar[rg]));                               \
            float z  = RCPF(1.f + EXP2F(az[rg]));                               \
            float np = ain[rg] + r * ahn[rg];    /* scaled by -2*log2e */       \
            float n  = 2.f * RCPF(1.f + EXP2F(np)) - 1.f;                       \
            float h  = n + z * (h_old[rg] - n);                                 \
            h_old[rg] = h;                                                      \
            if (quad < 2)                                                       \
                (WBUF)[(quad * 4 + rg) * 136 + w * 16 + nidx] = (half_t)h;      \
        }                                                                       \
        __syncthreads();                                                        \
    }

    for (int it = 0; it < 128; ++it) {
        xaB0 = *(const half8*)ap;
        xaB1 = *(const half8*)(ap + 32);
        ap += Ss;
        GRU_STEP(xaA0, xaA1, hbuf0, hbuf1)
        // last prefetch reads slightly past xt: stays inside d_out, unused
        xaA0 = *(const half8*)ap;
        xaA1 = *(const half8*)(ap + 32);
        ap += Ss;
        GRU_STEP(xaB0, xaB1, hbuf1, hbuf0)
    }
#undef GRU_STEP

    if (quad < 2) {
        int srow = (b << 8) + g8;
#pragma unroll
        for (int rg = 0; rg < 4; ++rg) {
            hout[(size_t)(srow + quad * 4 + rg) * H_ + w * 16 + nidx] = h_old[rg];
        }
    }
}

// ---------------- Kernel 3: out[b,c,t,f] = bp[c] + sum_h Wp[c,h]*(h_t[b,t,h]+h_f[b,t,h]) ----------------
__global__ __launch_bounds__(256) void k_out(const float* __restrict__ h_t,
                                             const float* __restrict__ h_f,
                                             const float* __restrict__ Wp,
                                             const float* __restrict__ bp,
                                             float* __restrict__ out) {
    __shared__ float sv[128];
    __shared__ float part[4][64];
    __shared__ float orow[64];
    int blk = blockIdx.x;
    int b = blk >> 8;
    int i = blk & 255;              // t index
    int tid = threadIdx.x;
    size_t hoff = ((size_t)(b * 256 + i)) * 128;
    if (tid < 128) sv[tid] = h_t[hoff + tid] + h_f[hoff + tid];
    __syncthreads();
    int c = tid & 63;
    int q = tid >> 6;
    float p = 0.f;
    const float* wp = Wp + c * 128 + q * 32;
#pragma unroll
    for (int k = 0; k < 32; ++k) p += wp[k] * sv[q * 32 + k];
    part[q][c] = p;
    __syncthreads();
    if (tid < 64) orow[tid] = part[0][tid] + part[1][tid] + part[2][tid] + part[3][tid] + bp[tid];
    __syncthreads();
    // wave wv writes full contiguous rows out[b, c, i, 0:256] (1 KB each)
    int wv   = tid >> 6;
    int lane = tid & 63;
#pragma unroll
    for (int itr = 0; itr < 16; ++itr) {
        int cc = itr * 4 + wv;
        float v = orow[cc];
        float4v vv = {v, v, v, v};
        *(float4v*)(out + (((size_t)(b * 64 + cc)) * 256 + i) * 256 + lane * 4) = vv;
    }
}

extern "C" void kernel_launch(void* const* d_in, const int* in_sizes, int n_in,
                              void* d_out, int out_size, void* d_ws, size_t ws_size,
                              hipStream_t stream) {
    const float* x     = (const float*)d_in[0];
    const float* Wih_t = (const float*)d_in[1];
    const float* Whh_t = (const float*)d_in[2];
    const float* bih_t = (const float*)d_in[3];
    const float* bhh_t = (const float*)d_in[4];
    const float* Wih_f = (const float*)d_in[5];
    const float* Whh_f = (const float*)d_in[6];
    const float* bih_f = (const float*)d_in[7];
    const float* bhh_f = (const float*)d_in[8];
    const float* Wp    = (const float*)d_in[9];
    const float* bp    = (const float*)d_in[10];
    float* out = (float*)d_out;

    // xt (fp16, 64 MiB) lives in d_out: fully consumed by k_gru before k_out
    // overwrites d_out with the final result. h_t/h_f (2 MiB) live in ws.
    half_t* xt     = (half_t*)d_out;
    float* h_t_out = (float*)((char*)d_ws);
    float* h_f_out = (float*)((char*)d_ws + (size_t)2048 * 128 * 4);

    k_transpose<<<8192, 256, 0, stream>>>(x, xt);
    k_gru<<<512, 512, 0, stream>>>(xt, Wih_t, Whh_t, bih_t, bhh_t,
                                   Wih_f, Whh_f, bih_f, bhh_f, h_t_out, h_f_out);
    k_out<<<2048, 256, 0, stream>>>(h_t_out, h_f_out, Wp, bp, out);
}

// Round 5
// 436.112 us; speedup vs baseline: 1.5212x; 1.5212x over previous
//
#include <hip/hip_runtime.h>

#define B_ 8
#define C_ 64
#define T_ 256
#define F_ 256
#define H_ 128
#define TF_ (T_*F_)

typedef _Float16 half_t;
typedef _Float16 half8 __attribute__((ext_vector_type(8)));
typedef float float4v __attribute__((ext_vector_type(4)));

#if __has_builtin(__builtin_amdgcn_exp2f)
#define EXP2F(x) __builtin_amdgcn_exp2f(x)
#else
static __device__ inline float EXP2F(float x) { float r; asm("v_exp_f32 %0, %1" : "=v"(r) : "v"(x)); return r; }
#endif
#if __has_builtin(__builtin_amdgcn_rcpf)
#define RCPF(x) __builtin_amdgcn_rcpf(x)
#else
static __device__ inline float RCPF(float x) { float r; asm("v_rcp_f32 %0, %1" : "=v"(r) : "v"(x)); return r; }
#endif

#define NEG_L2E  (-1.4426950408889634f)
#define NEG_2L2E (-2.8853900817779268f)

// ---------------- Kernel 1: x [B,C,T,F] fp32 -> xt [B, T*F, C] fp16 ----------------
__global__ __launch_bounds__(256) void k_transpose(const float* __restrict__ x,
                                                   half_t* __restrict__ xt) {
    __shared__ float lds[64 * 65];
    int blk = blockIdx.x;
    int b   = blk >> 10;            // /1024
    int tf0 = (blk & 1023) << 6;    // *64
    int tid = threadIdx.x;
    int s = tid & 15;               // tf sub-tile (x4)
    int q = tid >> 4;               // 0..15 c base
    const float* xp = x + (size_t)(b * C_) * TF_ + tf0 + s * 4;
#pragma unroll
    for (int i = 0; i < 4; ++i) {
        int c = q + i * 16;
        float4v v = *(const float4v*)(xp + (size_t)c * TF_);
#pragma unroll
        for (int j = 0; j < 4; ++j) lds[(s * 4 + j) * 65 + c] = v[j];
    }
    __syncthreads();
    int row = tid >> 2;             // 0..63 (tf local)
    int c0  = (tid & 3) << 4;       // 0,16,32,48
    float v[16];
#pragma unroll
    for (int k = 0; k < 16; ++k) v[k] = lds[row * 65 + c0 + k];
    half8 o0, o1;
#pragma unroll
    for (int k = 0; k < 8; ++k) { o0[k] = (half_t)v[k]; o1[k] = (half_t)v[8 + k]; }
    half_t* op = xt + ((size_t)b * TF_ + tf0 + row) * C_ + c0;
    *(half8*)op       = o0;
    *(half8*)(op + 8) = o1;
}

// ---------------- Kernel 2: fused dual GRU, MFMA 16x16x32 f16, M=16/block ----------------
__device__ inline half8 load_w8s(const float* __restrict__ p, float s) {
    half8 r;
#pragma unroll
    for (int k = 0; k < 8; ++k) r[k] = (half_t)(p[k] * s);
    return r;
}

#define MFMA(a, b, c) __builtin_amdgcn_mfma_f32_16x16x32_f16((a), (b), (c), 0, 0, 0)

// 256 blocks (128 time + 128 freq), 512 thr = 8 waves; block owns M=16 sequences.
// Wave w owns hidden units [16w,16w+16) (N-tiles r/z/n). 100% MFMA efficiency.
// x-part accumulators (gi = x.Wih, no h dependency) for step t+1 are refilled
// AFTER the h-write of step t, in the barrier shadow. Post-barrier h-MFMA chains
// are depth 2: r -> {xr,hr}, z -> {xz,hz}, n -> {hna,hnb} (n's h-product must
// stay entirely inside the r-multiplication: np = xn + r*(hna+hnb); hna seeds bhn).
// A-frag: lane holds A[m=lane&15][k=quad*8+j]; B-frag: B[k=quad*8+j][n=lane&15];
// C/D: lane holds D[m=quad*4+reg][n=lane&15].
__global__ __launch_bounds__(512, 2) void k_gru(
    const half_t* __restrict__ xt,
    const float* __restrict__ Wih_t, const float* __restrict__ Whh_t,
    const float* __restrict__ bih_t, const float* __restrict__ bhh_t,
    const float* __restrict__ Wih_f, const float* __restrict__ Whh_f,
    const float* __restrict__ bih_f, const float* __restrict__ bhh_f,
    float* __restrict__ h_t_out, float* __restrict__ h_f_out) {
    __shared__ half_t hbuf0[16 * 136];
    __shared__ half_t hbuf1[16 * 136];

    int tid  = threadIdx.x;
    int w    = tid >> 6;
    int lane = tid & 63;
    int nidx = lane & 15;
    int quad = lane >> 4;

    int bi  = blockIdx.x;
    bool isf = bi >= 128;
    int lbi = bi & 127;
    int b   = lbi >> 4;
    int g16 = (lbi & 15) << 4;    // f0 (time) or t0 (freq)

    const float* Wih = isf ? Wih_f : Wih_t;
    const float* Whh = isf ? Whh_f : Whh_t;
    const float* bih = isf ? bih_f : bih_t;
    const float* bhh = isf ? bhh_f : bhh_t;
    float* hout      = isf ? h_f_out : h_t_out;

    size_t Sm = isf ? (size_t)(F_ * C_) : (size_t)C_;   // stride between sequences
    size_t Ss = isf ? (size_t)C_ : (size_t)(F_ * C_);   // stride per recurrence step
    size_t abase = (size_t)b * TF_ * C_ + (size_t)g16 * Sm;

    // ---- weight B-fragments in registers (loaded once, pre-scaled) ----
    int gr = w * 16 + nidx;     // r gate row  [0,128)
    int gz = gr + 128;          // z gate row
    int gn = gr + 256;          // n gate row
    int ko = quad * 8;

    half8 wir0 = load_w8s(Wih + gr * 64 + ko,      NEG_L2E);
    half8 wir1 = load_w8s(Wih + gr * 64 + 32 + ko, NEG_L2E);
    half8 wiz0 = load_w8s(Wih + gz * 64 + ko,      NEG_L2E);
    half8 wiz1 = load_w8s(Wih + gz * 64 + 32 + ko, NEG_L2E);
    half8 win0 = load_w8s(Wih + gn * 64 + ko,      NEG_2L2E);
    half8 win1 = load_w8s(Wih + gn * 64 + 32 + ko, NEG_2L2E);
    half8 whr[4], whz[4], whn[4];
#pragma unroll
    for (int kt = 0; kt < 4; ++kt) {
        whr[kt] = load_w8s(Whh + gr * 128 + kt * 32 + ko, NEG_L2E);
        whz[kt] = load_w8s(Whh + gz * 128 + kt * 32 + ko, NEG_L2E);
        whn[kt] = load_w8s(Whh + gn * 128 + kt * 32 + ko, NEG_2L2E);
    }
    float br  = NEG_L2E  * (bih[gr] + bhh[gr]);
    float bz  = NEG_L2E  * (bih[gz] + bhh[gz]);
    float bin = NEG_2L2E * bih[gn];
    float bhn = NEG_2L2E * bhh[gn];

    for (int idx = tid; idx < 16 * 136; idx += 512) hbuf0[idx] = (half_t)0.f;
    float h_old[4] = {0.f, 0.f, 0.f, 0.f};

    const half_t* ap = xt + abase + (size_t)nidx * Sm + ko;
    half8 xA0 = *(const half8*)ap;          // x_0
    half8 xA1 = *(const half8*)(ap + 32);
    ap += Ss;
    half8 xB0 = *(const half8*)ap;          // x_1
    half8 xB1 = *(const half8*)(ap + 32);
    ap += Ss;

    // x-part accumulators for step 0 (from x_0)
    float4v xr = {br, br, br, br};
    float4v xz = {bz, bz, bz, bz};
    float4v xn = {bin, bin, bin, bin};
    xr = MFMA(xA0, wir0, xr); xr = MFMA(xA1, wir1, xr);
    xz = MFMA(xA0, wiz0, xz); xz = MFMA(xA1, wiz1, xz);
    xn = MFMA(xA0, win0, xn); xn = MFMA(xA1, win1, xn);
    __syncthreads();

    // XC0/XC1: x regs for the NEXT step's xacc refill (consumed in shadow);
    // XP0/XP1: x regs being prefetched for t+2.
#define GRU_STEP(RBUF, WBUF, XC0, XC1, XP0, XP1)                                \
    {                                                                           \
        const half_t* hrow = (RBUF) + nidx * 136 + ko;                          \
        half8 ha0 = *(const half8*)(hrow);                                      \
        half8 ha1 = *(const half8*)(hrow + 32);                                 \
        half8 ha2 = *(const half8*)(hrow + 64);                                 \
        half8 ha3 = *(const half8*)(hrow + 96);                                 \
        XP0 = *(const half8*)ap;                                                \
        XP1 = *(const half8*)(ap + 32);                                         \
        ap += Ss;                                                               \
        float4v hr  = {0.f, 0.f, 0.f, 0.f};                                     \
        float4v hz  = {0.f, 0.f, 0.f, 0.f};                                     \
        float4v hna = {bhn, bhn, bhn, bhn};                                     \
        float4v hnb = {0.f, 0.f, 0.f, 0.f};                                     \
        xr  = MFMA(ha0, whr[0], xr);  xr  = MFMA(ha1, whr[1], xr);              \
        hr  = MFMA(ha2, whr[2], hr);  hr  = MFMA(ha3, whr[3], hr);              \
        xz  = MFMA(ha0, whz[0], xz);  xz  = MFMA(ha1, whz[1], xz);              \
        hz  = MFMA(ha2, whz[2], hz);  hz  = MFMA(ha3, whz[3], hz);              \
        hna = MFMA(ha0, whn[0], hna); hna = MFMA(ha1, whn[1], hna);             \
        hnb = MFMA(ha2, whn[2], hnb); hnb = MFMA(ha3, whn[3], hnb);             \
        _Pragma("unroll")                                                       \
        for (int rg = 0; rg < 4; ++rg) {                                        \
            float r  = RCPF(1.f + EXP2F(xr[rg] + hr[rg]));                      \
            float z  = RCPF(1.f + EXP2F(xz[rg] + hz[rg]));                      \
            float np = xn[rg] + r * (hna[rg] + hnb[rg]);                        \
            float n  = 2.f * RCPF(1.f + EXP2F(np)) - 1.f;                       \
            float h  = n + z * (h_old[rg] - n);                                 \
            h_old[rg] = h;                                                      \
            (WBUF)[(quad * 4 + rg) * 136 + w * 16 + nidx] = (half_t)h;          \
        }                                                                       \
        /* barrier shadow: refill x-part accumulators for the next step */      \
        xr[0] = br;  xr[1] = br;  xr[2] = br;  xr[3] = br;                      \
        xz[0] = bz;  xz[1] = bz;  xz[2] = bz;  xz[3] = bz;                      \
        xn[0] = bin; xn[1] = bin; xn[2] = bin; xn[3] = bin;                     \
        xr = MFMA(XC0, wir0, xr); xr = MFMA(XC1, wir1, xr);                     \
        xz = MFMA(XC0, wiz0, xz); xz = MFMA(XC1, wiz1, xz);                     \
        xn = MFMA(XC0, win0, xn); xn = MFMA(XC1, win1, xn);                     \
        __syncthreads();                                                        \
    }

    for (int it = 0; it < 128; ++it) {
        // step t=2it: reads hbuf0, writes hbuf1; xacc refilled from xB (x_{t+1}); prefetch into xA
        GRU_STEP(hbuf0, hbuf1, xB0, xB1, xA0, xA1)
        // step t=2it+1: reads hbuf1, writes hbuf0; refilled from xA; prefetch into xB
        // (tail prefetches/xacc read past xt but stay inside d_out: harmless, unused)
        GRU_STEP(hbuf1, hbuf0, xA0, xA1, xB0, xB1)
    }
#undef GRU_STEP

    int srow = (b << 8) + g16;
#pragma unroll
    for (int rg = 0; rg < 4; ++rg) {
        hout[(size_t)(srow + quad * 4 + rg) * H_ + w * 16 + nidx] = h_old[rg];
    }
}

// ---------------- Kernel 3: out[b,c,t,f] = bp[c] + sum_h Wp[c,h]*(h_t[b,t,h]+h_f[b,t,h]) ----------------
__global__ __launch_bounds__(256) void k_out(const float* __restrict__ h_t,
                                             const float* __restrict__ h_f,
                                             const float* __restrict__ Wp,
                                             const float* __restrict__ bp,
                                             float* __restrict__ out) {
    __shared__ float sv[128];
    __shared__ float part[4][64];
    __shared__ float orow[64];
    int blk = blockIdx.x;
    int b = blk >> 8;
    int i = blk & 255;              // t index
    int tid = threadIdx.x;
    size_t hoff = ((size_t)(b * 256 + i)) * 128;
    if (tid < 128) sv[tid] = h_t[hoff + tid] + h_f[hoff + tid];
    __syncthreads();
    int c = tid & 63;
    int q = tid >> 6;
    float p = 0.f;
    const float* wp = Wp + c * 128 + q * 32;
#pragma unroll
    for (int k = 0; k < 32; ++k) p += wp[k] * sv[q * 32 + k];
    part[q][c] = p;
    __syncthreads();
    if (tid < 64) orow[tid] = part[0][tid] + part[1][tid] + part[2][tid] + part[3][tid] + bp[tid];
    __syncthreads();
    // wave wv writes full contiguous rows out[b, c, i, 0:256] (1 KB each)
    int wv   = tid >> 6;
    int lane = tid & 63;
#pragma unroll
    for (int itr = 0; itr < 16; ++itr) {
        int cc = itr * 4 + wv;
        float v = orow[cc];
        float4v vv = {v, v, v, v};
        *(float4v*)(out + (((size_t)(b * 64 + cc)) * 256 + i) * 256 + lane * 4) = vv;
    }
}

extern "C" void kernel_launch(void* const* d_in, const int* in_sizes, int n_in,
                              void* d_out, int out_size, void* d_ws, size_t ws_size,
                              hipStream_t stream) {
    const float* x     = (const float*)d_in[0];
    const float* Wih_t = (const float*)d_in[1];
    const float* Whh_t = (const float*)d_in[2];
    const float* bih_t = (const float*)d_in[3];
    const float* bhh_t = (const float*)d_in[4];
    const float* Wih_f = (const float*)d_in[5];
    const float* Whh_f = (const float*)d_in[6];
    const float* bih_f = (const float*)d_in[7];
    const float* bhh_f = (const float*)d_in[8];
    const float* Wp    = (const float*)d_in[9];
    const float* bp    = (const float*)d_in[10];
    float* out = (float*)d_out;

    // xt (fp16, 64 MiB) lives in the first half of d_out (128 MiB): fully
    // consumed by k_gru before k_out overwrites d_out. h_t/h_f live in ws.
    half_t* xt     = (half_t*)d_out;
    float* h_t_out = (float*)((char*)d_ws);
    float* h_f_out = (float*)((char*)d_ws + (size_t)2048 * 128 * 4);

    k_transpose<<<8192, 256, 0, stream>>>(x, xt);
    k_gru<<<256, 512, 0, stream>>>(xt, Wih_t, Whh_t, bih_t, bhh_t,
                                   Wih_f, Whh_f, bih_f, bhh_f, h_t_out, h_f_out);
    k_out<<<2048, 256, 0, stream>>>(h_t_out, h_f_out, Wp, bp, out);
}